// Round 3
// baseline (32.267 us; speedup 1.0000x reference)
//
#include <hip/hip_runtime.h>
#include <hip/hip_cooperative_groups.h>

namespace cg = cooperative_groups;

// MiniBatchAUC: loss = sum_{i in pos, j in neg} (1 - (s_i - s_j))^2 / (n_pos*n_neg),
// s = sigmoid(logits). Closed form in 6 O(N) reductions:
//   loss_total = np*nn - 2*nn*Sp + 2*np*Sn + nn*Sp2 + np*Sn2 - 2*Sp*Sn
//
// Single COOPERATIVE dispatch: 64 blocks x 64 threads spread the 384 KB of
// loads across 64 CUs (round 1's single-CU VMEM serialization removed),
// grid.sync(), then block 0 combines the 64x6 partials in double.
// One dispatch -> no dependent-dispatch gap (round 2 cost +0.5 us for that).

#define GRID 64
#define BLK  64

__global__ __launch_bounds__(BLK) void auc_fused_kernel(
    const float* __restrict__ logits, const int* __restrict__ targets,
    float* __restrict__ ws, float* __restrict__ out, int n) {
  const int tid  = threadIdx.x;
  const int gtid = blockIdx.x * BLK + tid;
  const int nthreads = GRID * BLK;

  // acc: [0]=n_pos [1]=n_neg [2]=Sp [3]=Sn [4]=Sp2 [5]=Sn2
  float acc[6] = {0.f, 0.f, 0.f, 0.f, 0.f, 0.f};

  const int n4 = n >> 2;
  const float4* l4 = reinterpret_cast<const float4*>(logits);
  const int4*   t4 = reinterpret_cast<const int4*>(targets);

  for (int i = gtid; i < n4; i += nthreads) {  // exactly one iter at N=16384
    float4 lv = l4[i];
    int4   tv = t4[i];
    float xs[4] = {lv.x, lv.y, lv.z, lv.w};
    int   ts[4] = {tv.x, tv.y, tv.z, tv.w};
#pragma unroll
    for (int k = 0; k < 4; ++k) {
      float s  = 1.0f / (1.0f + __expf(-xs[k]));
      float s2 = s * s;
      float p  = (ts[k] != 0) ? 1.0f : 0.0f;  // predicated, no divergence
      float q  = 1.0f - p;
      acc[0] += p;       acc[1] += q;
      acc[2] += p * s;   acc[3] += q * s;
      acc[4] += p * s2;  acc[5] += q * s2;
    }
  }
  // scalar tail for n % 4 != 0 (not hit at N=16384)
  for (int i = (n4 << 2) + gtid; i < n; i += nthreads) {
    float s  = 1.0f / (1.0f + __expf(-logits[i]));
    float s2 = s * s;
    float p  = (targets[i] != 0) ? 1.0f : 0.0f;
    float q  = 1.0f - p;
    acc[0] += p;       acc[1] += q;
    acc[2] += p * s;   acc[3] += q * s;
    acc[4] += p * s2;  acc[5] += q * s2;
  }

  // wave-64 butterfly reduce (block == one wave)
#pragma unroll
  for (int j = 0; j < 6; ++j) {
#pragma unroll
    for (int m = 1; m < 64; m <<= 1) {
      acc[j] += __shfl_xor(acc[j], m, 64);
    }
  }

  if (tid == 0) {
#pragma unroll
    for (int j = 0; j < 6; ++j) ws[blockIdx.x * 6 + j] = acc[j];
  }

  cg::this_grid().sync();  // device-scope: ws visible to block 0

  if (blockIdx.x == 0) {
    // one partial-set per lane, combine in double (fixed order, deterministic)
    double t[6];
#pragma unroll
    for (int j = 0; j < 6; ++j) t[j] = (double)ws[tid * 6 + j];

#pragma unroll
    for (int j = 0; j < 6; ++j) {
#pragma unroll
      for (int m = 1; m < 64; m <<= 1) {
        t[j] += __shfl_xor(t[j], m, 64);
      }
    }

    if (tid == 0) {
      double np_ = t[0], nn = t[1], sp = t[2], sn = t[3], sp2 = t[4], sn2 = t[5];
      double loss = np_ * nn
                  - 2.0 * nn * sp
                  + 2.0 * np_ * sn
                  + nn * sp2
                  + np_ * sn2
                  - 2.0 * sp * sn;
      out[0] = (float)(loss / (np_ * nn));
    }
  }
}

extern "C" void kernel_launch(void* const* d_in, const int* in_sizes, int n_in,
                              void* d_out, int out_size, void* d_ws, size_t ws_size,
                              hipStream_t stream) {
  const float* logits  = (const float*)d_in[0];
  const int*   targets = (const int*)d_in[1];
  float*       out     = (float*)d_out;
  float*       ws      = (float*)d_ws;   // needs GRID*6 floats = 1.5 KB
  int n = in_sizes[0];

  void* args[] = {(void*)&logits, (void*)&targets, (void*)&ws, (void*)&out, (void*)&n};
  hipLaunchCooperativeKernel((const void*)auc_fused_kernel,
                             dim3(GRID), dim3(BLK), args, 0, stream);
}

// Round 4
// 10.434 us; speedup vs baseline: 3.0924x; 3.0924x over previous
//
#include <hip/hip_runtime.h>

// MiniBatchAUC: loss = sum_{i in pos, j in neg} (1 - (s_i - s_j))^2 / (n_pos*n_neg),
// s = sigmoid(logits). Closed form via O(N) sufficient statistics:
//   np, Sp = sum_pos s, Sp2 = sum_pos s^2, S = sum s, S2 = sum s^2
//   nn = N-np, Sn = S-Sp, Sn2 = S2-Sp2
//   loss_total = np*nn - 2*nn*Sp + 2*np*Sn + nn*Sp2 + np*Sn2 - 2*Sp*Sn
//
// Round history: R1 single plain dispatch = 10.77 us; R2 two dispatches =
// 11.26 us (+0.5 us/dispatch); R3 cooperative = 32.27 us (grid.sync ~+21 us).
// Kernel work is ~1-2 us; dur_us is dominated by the ~10 us graph-replay /
// launch overhead floor. -> Single plain dispatch, one block, 5 reductions.

#define BLOCK 1024

__global__ __launch_bounds__(BLOCK) void auc_stats_kernel(
    const float* __restrict__ logits, const int* __restrict__ targets,
    float* __restrict__ out, int n) {
  const int tid = threadIdx.x;

  // acc: [0]=np [1]=Sp [2]=Sp2 [3]=S [4]=S2
  float acc[5] = {0.f, 0.f, 0.f, 0.f, 0.f};

  const int n4 = n >> 2;
  const float4* l4 = reinterpret_cast<const float4*>(logits);
  const int4*   t4 = reinterpret_cast<const int4*>(targets);

  for (int i = tid; i < n4; i += BLOCK) {
    float4 lv = l4[i];
    int4   tv = t4[i];
    float xs[4] = {lv.x, lv.y, lv.z, lv.w};
    int   ts[4] = {tv.x, tv.y, tv.z, tv.w};
#pragma unroll
    for (int k = 0; k < 4; ++k) {
      float s  = 1.0f / (1.0f + __expf(-xs[k]));
      float s2 = s * s;
      float p  = (ts[k] != 0) ? 1.0f : 0.0f;  // predicated, no divergence
      acc[0] += p;
      acc[1] += p * s;
      acc[2] += p * s2;
      acc[3] += s;
      acc[4] += s2;
    }
  }
  // scalar tail for n % 4 != 0 (not hit at N=16384)
  for (int i = (n4 << 2) + tid; i < n; i += BLOCK) {
    float s  = 1.0f / (1.0f + __expf(-logits[i]));
    float s2 = s * s;
    float p  = (targets[i] != 0) ? 1.0f : 0.0f;
    acc[0] += p;
    acc[1] += p * s;
    acc[2] += p * s2;
    acc[3] += s;
    acc[4] += s2;
  }

  // wave-64 butterfly reduce
#pragma unroll
  for (int j = 0; j < 5; ++j) {
#pragma unroll
    for (int m = 1; m < 64; m <<= 1) {
      acc[j] += __shfl_xor(acc[j], m, 64);
    }
  }

  __shared__ float lds[BLOCK / 64][5];
  const int wave = tid >> 6;
  const int lane = tid & 63;
  if (lane == 0) {
#pragma unroll
    for (int j = 0; j < 5; ++j) lds[wave][j] = acc[j];
  }
  __syncthreads();

  if (tid == 0) {
    double t[5] = {0, 0, 0, 0, 0};
    for (int w = 0; w < BLOCK / 64; ++w)
      for (int j = 0; j < 5; ++j) t[j] += (double)lds[w][j];

    double np_ = t[0], sp = t[1], sp2 = t[2], S = t[3], S2 = t[4];
    double nn  = (double)n - np_;
    double sn  = S - sp;
    double sn2 = S2 - sp2;
    double loss = np_ * nn
                - 2.0 * nn * sp
                + 2.0 * np_ * sn
                + nn * sp2
                + np_ * sn2
                - 2.0 * sp * sn;
    out[0] = (float)(loss / (np_ * nn));
  }
}

extern "C" void kernel_launch(void* const* d_in, const int* in_sizes, int n_in,
                              void* d_out, int out_size, void* d_ws, size_t ws_size,
                              hipStream_t stream) {
  const float* logits  = (const float*)d_in[0];
  const int*   targets = (const int*)d_in[1];
  float*       out     = (float*)d_out;
  const int n = in_sizes[0];

  auc_stats_kernel<<<dim3(1), dim3(BLOCK), 0, stream>>>(logits, targets, out, n);
}